// Round 14
// baseline (105.182 us; speedup 1.0000x reference)
//
#include <hip/hip_runtime.h>

// EFDM loss — reduced form:
//   pos_sum[b]  = sum over (a,p,c,j) of (sortT[a,p,b,c][j] - sortS[a,p,b,c][j])^2
//   neg_sum[b]  = sum over (a,p,k,c,j) of (sortT[a,p,b,c][j] - sortS[a,p,nb(b,k),c][j])^2
//   out = sum_b pos_sum[b]/neg_sum[b]          (the 1/(C*N) mean factors cancel)
//
// Kernel 1 (sort_pair): 4096 blocks, block r sorts BOTH S-row r and T-row r in
// one instruction stream (word = [S elem lo, T elem hi]); NEW: computes the
// pos-term in the epilogue (rank-aligned halves -> pk_sub + dot2) and writes
// pospart[r]. Sort network unchanged from R13 (proven).
// Kernel 2 (diff_rows): neg terms only; grid XCD-chunked so each XCD's 512
// rows (one ap-chunk) reuse their neg-S rows from its private L2.
// Kernel 3 (finalize): one-block double reduction of pospart/negpart.

typedef unsigned int u32;
typedef __fp16 f16x2 __attribute__((ext_vector_type(2)));

constexpr int N     = 4096;
constexpr int NTH   = 256;
constexpr int CDIM  = 128;
constexpr int BDIM  = 4;
constexpr int KNEG  = 2;
constexpr int ROWS  = 4096;
constexpr int HALF  = 2048;
constexpr int ROWW  = N / 2;   // 2048 packed words per row
constexpr int LSTRW = 20;      // words per thread slot in LDS (80B; 16 used)
constexpr int LDSW  = NTH * LSTRW;   // 20480 B -> 8 blocks/CU

__device__ inline int lslot(int t) { return t * LSTRW; }

// ---------- packed fp16 primitives ----------
__device__ inline u32 pk_min(u32 a, u32 b) {
  u32 d; asm("v_pk_min_f16 %0, %1, %2" : "=v"(d) : "v"(a), "v"(b)); return d;
}
__device__ inline u32 pk_max(u32 a, u32 b) {
  u32 d; asm("v_pk_max_f16 %0, %1, %2" : "=v"(d) : "v"(a), "v"(b)); return d;
}
__device__ inline u32 pk_min_negb(u32 a, u32 b) {   // min(a, -b) per half
  u32 d; asm("v_pk_min_f16 %0, %1, %2 neg_lo:[0,1] neg_hi:[0,1]" : "=v"(d) : "v"(a), "v"(b)); return d;
}
__device__ inline u32 pk_sub(u32 a, u32 b) {   // a - b per half
  u32 d; asm("v_pk_add_f16 %0, %1, %2 neg_lo:[0,1] neg_hi:[0,1]" : "=v"(d) : "v"(a), "v"(b)); return d;
}
__device__ inline float dot2acc(u32 d, float acc) {  // acc += d.lo^2 + d.hi^2
  asm("v_dot2_f32_f16 %0, %1, %2, %0" : "+v"(acc) : "v"(d), "v"(d)); return acc;
}
__device__ inline void pk_cswap(u32& a, u32& b) {
  const u32 mn = pk_min(a, b), mx = pk_max(a, b);
  a = mn; b = mx;
}

// ---------- cross-lane moves ----------
// DPP ctrls: 0xB1=quad xor1, 0x4E=quad xor2, 0x128=row_ror:8 (xor8)
template<int CTRL>
__device__ inline u32 dpp_u(u32 x) {
  return (u32)__builtin_amdgcn_update_dpp((int)x, (int)x, CTRL, 0xF, 0xF, false);
}
template<int TM>
__device__ inline u32 dppx(u32 x) {   // value from lane t^TM
  if constexpr (TM == 1)      return dpp_u<0xB1>(x);
  else if constexpr (TM == 2) return dpp_u<0x4E>(x);
  else if constexpr (TM == 4)   // xor4 via ds_swizzle (DS pipe)
    return (u32)__builtin_amdgcn_ds_swizzle((int)x, 0x101F);
  else                        return dpp_u<0x128>(x);
}
__device__ inline void swap32u(u32& a, u32& b) {
  asm("v_permlane32_swap_b32 %0, %1" : "+v"(a), "+v"(b));
}
__device__ inline void swap16u(u32& a, u32& b) {
  asm("v_permlane16_swap_b32 %0, %1" : "+v"(a), "+v"(b));
}

__device__ inline void flip16(u32 h[16], u32 f) {
  #pragma unroll
  for (int p = 0; p < 16; ++p) h[p] ^= f;
}

// ---------- polarized exchange block (on 16 words) ----------
// Stored H(t) = sigma_TM(t) * x(t), sigma=+1 iff (t&TM)==0. Partner has the
// opposite sigma: H' = pk_min(H, -xchg(H)) with the negate fused.
struct PolM { u32 s1, s2, s4, s8; };

template<int TM>
__device__ inline void polar_pass16(u32 h[16]) {
  #pragma unroll
  for (int g = 0; g < 16; g += 8) {
    u32 o[8];
    #pragma unroll
    for (int p = 0; p < 8; ++p) o[p] = dppx<TM>(h[g + p]);
    #pragma unroll
    for (int p = 0; p < 8; ++p) h[g + p] = pk_min_negb(h[g + p], o[p]);
  }
}

template<int TMS, bool SKIP_ENTRY>
__device__ inline void polar_block16(u32 h[16], const PolM& pm) {
  if constexpr (!SKIP_ENTRY) {
    const u32 e = (TMS == 8) ? pm.s8 : (TMS == 4) ? pm.s4 : (TMS == 2) ? pm.s2 : pm.s1;
    flip16(h, e);
  }
  if constexpr (TMS >= 8) { polar_pass16<8>(h); flip16(h, pm.s8 ^ pm.s4); }
  if constexpr (TMS >= 4) { polar_pass16<4>(h); flip16(h, pm.s4 ^ pm.s2); }
  if constexpr (TMS >= 2) { polar_pass16<2>(h); flip16(h, pm.s2 ^ pm.s1); }
  polar_pass16<1>(h);
  flip16(h, pm.s1);   // back to plain
}

// lane-xor 16/32 butterfly on word PAIRs: positional min/max, no polarity
template<bool IS32>
__device__ inline void pass_perm16(u32 h[16]) {
  #pragma unroll
  for (int q = 0; q < 8; ++q) {
    u32 a = h[2*q], b = h[2*q + 1];
    if constexpr (IS32) swap32u(a, b); else swap16u(a, b);
    u32 mn = pk_min(a, b);
    u32 mx = pk_max(a, b);
    if constexpr (IS32) swap32u(mn, mx); else swap16u(mn, mx);
    h[2*q] = mn; h[2*q + 1] = mx;
  }
}

// thread-xor 64/128 via LDS; keep decision wave-uniform
template<int TM>
__device__ inline void pass_lds16(u32 h[16], u32* buf, int t) {
  __syncthreads();   // protect prior reads of buf
  uint4* wp = (uint4*)(buf + lslot(t));
  wp[0] = make_uint4(h[0],  h[1],  h[2],  h[3]);
  wp[1] = make_uint4(h[4],  h[5],  h[6],  h[7]);
  wp[2] = make_uint4(h[8],  h[9],  h[10], h[11]);
  wp[3] = make_uint4(h[12], h[13], h[14], h[15]);
  __syncthreads();
  const uint4* rp = (const uint4*)(buf + lslot(t ^ TM));
  const uint4 x0 = rp[0], x1 = rp[1], x2 = rp[2], x3 = rp[3];
  if (t & TM) {
    h[0]  = pk_max(h[0],  x0.x); h[1]  = pk_max(h[1],  x0.y);
    h[2]  = pk_max(h[2],  x0.z); h[3]  = pk_max(h[3],  x0.w);
    h[4]  = pk_max(h[4],  x1.x); h[5]  = pk_max(h[5],  x1.y);
    h[6]  = pk_max(h[6],  x1.z); h[7]  = pk_max(h[7],  x1.w);
    h[8]  = pk_max(h[8],  x2.x); h[9]  = pk_max(h[9],  x2.y);
    h[10] = pk_max(h[10], x2.z); h[11] = pk_max(h[11], x2.w);
    h[12] = pk_max(h[12], x3.x); h[13] = pk_max(h[13], x3.y);
    h[14] = pk_max(h[14], x3.z); h[15] = pk_max(h[15], x3.w);
  } else {
    h[0]  = pk_min(h[0],  x0.x); h[1]  = pk_min(h[1],  x0.y);
    h[2]  = pk_min(h[2],  x0.z); h[3]  = pk_min(h[3],  x0.w);
    h[4]  = pk_min(h[4],  x1.x); h[5]  = pk_min(h[5],  x1.y);
    h[6]  = pk_min(h[6],  x1.z); h[7]  = pk_min(h[7],  x1.w);
    h[8]  = pk_min(h[8],  x2.x); h[9]  = pk_min(h[9],  x2.y);
    h[10] = pk_min(h[10], x2.z); h[11] = pk_min(h[11], x2.w);
    h[12] = pk_min(h[12], x3.x); h[13] = pk_min(h[13], x3.y);
    h[14] = pk_min(h[14], x3.z); h[15] = pk_min(h[15], x3.w);
  }
}

// pre-stage passes (k<=8): direction static from word index p
template<int K, int J>
__device__ inline void local_pass16(u32 h[16]) {
  #pragma unroll
  for (int p = 0; p < 16; ++p)
    if ((p & J) == 0) {
      if ((p & K) == 0) pk_cswap(h[p], h[p ^ J]);
      else              pk_cswap(h[p ^ J], h[p]);
    }
}

// in-register ascending tail: j = 8, 4, 2, 1 — all plain word-pair cswaps
__device__ inline void tail16(u32 h[16]) {
  #pragma unroll
  for (int p = 0; p < 16; ++p) if ((p & 8) == 0) pk_cswap(h[p], h[p ^ 8]);
  #pragma unroll
  for (int p = 0; p < 16; ++p) if ((p & 4) == 0) pk_cswap(h[p], h[p ^ 4]);
  #pragma unroll
  for (int p = 0; p < 16; ++p) if ((p & 2) == 0) pk_cswap(h[p], h[p ^ 2]);
  #pragma unroll
  for (int p = 0; p < 16; ++p) if ((p & 1) == 0) pk_cswap(h[p], h[p ^ 1]);
}

// one bitonic stage of width K (>=16), in sign-flipped space
template<int K>
__device__ inline void stage16(u32 h[16], u32* buf, int t, u32& cur, const PolM& pm) {
  constexpr bool FOLD = (K >= 32 && K <= 256);   // fold polar entry into flip
  const u32 f = (K >= 4096) ? 0u : ((t & (K >> 4)) ? 0x80008000u : 0u);
  u32 m = f ^ cur;
  if constexpr (FOLD)
    m ^= (K == 256) ? pm.s8 : (K == 128) ? pm.s4 : (K == 64) ? pm.s2 : pm.s1;
  flip16(h, m);
  cur = f;
  if constexpr (K >= 4096) pass_lds16<128>(h, buf, t);
  if constexpr (K >= 2048) pass_lds16<64>(h, buf, t);
  if constexpr (K >= 1024) pass_perm16<true>(h);
  if constexpr (K >= 512)  pass_perm16<false>(h);
  if constexpr (K >= 256)      polar_block16<8, FOLD>(h, pm);
  else if constexpr (K >= 128) polar_block16<4, FOLD>(h, pm);
  else if constexpr (K >= 64)  polar_block16<2, FOLD>(h, pm);
  else if constexpr (K >= 32)  polar_block16<1, FOLD>(h, pm);
  tail16(h);
}

// kernel 1: 4096 blocks; block r sorts S-row r (lo) + T-row r (hi), writes both
// packed sorted rows AND the pos-term partial for row r.
__global__ __launch_bounds__(NTH)
void sort_pair(const float* __restrict__ sE, const float* __restrict__ sS,
               const float* __restrict__ tE, const float* __restrict__ tS,
               u32* __restrict__ Ss, u32* __restrict__ Ts,
               float* __restrict__ pospart) {
  __shared__ u32 buf[LDSW];
  const int t = threadIdx.x, r = blockIdx.x;
  const float* srcS = (r < HALF) ? sE + (size_t)r * N : sS + (size_t)(r - HALF) * N;
  const float* srcT = (r < HALF) ? tE + (size_t)r * N : tS + (size_t)(r - HALF) * N;

  // load + pack: word p = [S elem t*16+p (lo), T elem t*16+p (hi)]
  u32 h[16];
  {
    const float4* a4 = (const float4*)srcS;
    const float4* b4 = (const float4*)srcT;
    #pragma unroll
    for (int q = 0; q < 4; ++q) {
      const float4 xa = a4[t*4 + q];
      const float4 xb = b4[t*4 + q];
      const f16x2 p0 = __builtin_amdgcn_cvt_pkrtz(xa.x, xb.x);
      const f16x2 p1 = __builtin_amdgcn_cvt_pkrtz(xa.y, xb.y);
      const f16x2 p2 = __builtin_amdgcn_cvt_pkrtz(xa.z, xb.z);
      const f16x2 p3 = __builtin_amdgcn_cvt_pkrtz(xa.w, xb.w);
      h[q*4+0] = __builtin_bit_cast(u32, p0);
      h[q*4+1] = __builtin_bit_cast(u32, p1);
      h[q*4+2] = __builtin_bit_cast(u32, p2);
      h[q*4+3] = __builtin_bit_cast(u32, p3);
    }
  }

  // pre-stages k=2,4,8 (directions static by word index; desc = swapped args)
  local_pass16<2, 1>(h);
  local_pass16<4, 2>(h); local_pass16<4, 1>(h);
  local_pass16<8, 4>(h); local_pass16<8, 2>(h); local_pass16<8, 1>(h);

  const u32 S = 0x80008000u;
  PolM pm;
  pm.s1 = (t & 1) ? S : 0u;  pm.s2 = (t & 2) ? S : 0u;
  pm.s4 = (t & 4) ? S : 0u;  pm.s8 = (t & 8) ? S : 0u;

  u32 cur = 0;
  stage16<16>(h, buf, t, cur, pm);
  stage16<32>(h, buf, t, cur, pm);
  stage16<64>(h, buf, t, cur, pm);
  stage16<128>(h, buf, t, cur, pm);
  stage16<256>(h, buf, t, cur, pm);
  stage16<512>(h, buf, t, cur, pm);
  stage16<1024>(h, buf, t, cur, pm);
  stage16<2048>(h, buf, t, cur, pm);
  stage16<4096>(h, buf, t, cur, pm);
  // cur == 0 at the end (stage 4096 has f == 0 for all t)

  // unpack: A-word q = [lo(h[2q]), lo(h[2q+1])], B-word q = [hi(h[2q]), hi(h[2q+1])]
  u32 A[8], B[8];
  #pragma unroll
  for (int q = 0; q < 8; ++q) {
    A[q] = __builtin_amdgcn_perm(h[2*q+1], h[2*q], 0x05040100u);
    B[q] = __builtin_amdgcn_perm(h[2*q+1], h[2*q], 0x07060302u);
  }
  uint4* dA = (uint4*)(Ss + (size_t)r * ROWW);
  uint4* dB = (uint4*)(Ts + (size_t)r * ROWW);
  dA[t]       = make_uint4(A[0], A[1], A[2], A[3]);
  dA[NTH + t] = make_uint4(A[4], A[5], A[6], A[7]);
  dB[t]       = make_uint4(B[0], B[1], B[2], B[3]);
  dB[NTH + t] = make_uint4(B[4], B[5], B[6], B[7]);

  // pos-term: halves are rank-aligned -> sum (T[i]-S[i])^2 right here
  float posp = 0.f;
  #pragma unroll
  for (int q = 0; q < 8; ++q) posp = dot2acc(pk_sub(B[q], A[q]), posp);
  #pragma unroll
  for (int off = 32; off > 0; off >>= 1) posp += __shfl_down(posp, off, 64);
  __syncthreads();                 // buf no longer needed as sort scratch
  float* fred = (float*)buf;
  const int wid = t >> 6, lane = t & 63;
  if (lane == 0) fred[wid] = posp;
  __syncthreads();
  if (t == 0) pospart[r] = fred[0] + fred[1] + fred[2] + fred[3];
}

// kernel 2: neg terms only. Grid XCD-chunked: r = (bid&7)*512 + (bid>>3) so
// each XCD owns one ap-chunk; its 512 rows' neg-S sources all live in that
// same chunk (4MB packed) -> L2-resident reuse.
__global__ __launch_bounds__(NTH)
void diff_rows(const u32* __restrict__ Ss, const u32* __restrict__ Ts,
               const int* __restrict__ neg_idx, float* __restrict__ negpart) {
  __shared__ float red[4];
  const int t = threadIdx.x;
  const int bid = blockIdx.x;
  const int r = ((bid & 7) << 9) + (bid >> 3);

  const uint4* tp = (const uint4*)(Ts + (size_t)r * ROWW);
  const uint4 h0 = tp[t], h1 = tp[NTH + t];

  // r = ((ap)*B + b)*C + c
  const int c  = r & (CDIM - 1);
  const int b  = (r / CDIM) & (BDIM - 1);
  const int ap = r / (CDIM * BDIM);

  float negp = 0.f;
  #pragma unroll
  for (int k = 0; k < KNEG; ++k) {
    const int nb = neg_idx[b * KNEG + k];
    const uint4* vp = (const uint4*)(Ss + ((size_t)(ap * BDIM + nb) * CDIM + c) * ROWW);
    const uint4 w0 = vp[t], w1 = vp[NTH + t];
    negp = dot2acc(pk_sub(h0.x, w0.x), negp);
    negp = dot2acc(pk_sub(h0.y, w0.y), negp);
    negp = dot2acc(pk_sub(h0.z, w0.z), negp);
    negp = dot2acc(pk_sub(h0.w, w0.w), negp);
    negp = dot2acc(pk_sub(h1.x, w1.x), negp);
    negp = dot2acc(pk_sub(h1.y, w1.y), negp);
    negp = dot2acc(pk_sub(h1.z, w1.z), negp);
    negp = dot2acc(pk_sub(h1.w, w1.w), negp);
  }

  #pragma unroll
  for (int off = 32; off > 0; off >>= 1) negp += __shfl_down(negp, off, 64);
  const int wid = t >> 6, lane = t & 63;
  if (lane == 0) red[wid] = negp;
  __syncthreads();
  if (t == 0) negpart[r] = red[0] + red[1] + red[2] + red[3];
}

// kernel 3: single-block reduction of 4096 partials, keyed by b
__global__ __launch_bounds__(NTH)
void finalize(const float* __restrict__ pospart, const float* __restrict__ negpart,
              float* __restrict__ out) {
  __shared__ double rp[4], rn[4];
  const int t = threadIdx.x;
  const int wid = t >> 6, lane = t & 63;
  double res = 0.0;
  #pragma unroll
  for (int b = 0; b < BDIM; ++b) {
    double p = 0.0, n = 0.0;
    for (int idx = t; idx < 1024; idx += NTH) {     // 8 ap-chunks x 128 c
      const int a = idx >> 7, c = idx & 127;
      const int rr = a * 512 + b * 128 + c;
      p += (double)pospart[rr];
      n += (double)negpart[rr];
    }
    #pragma unroll
    for (int off = 32; off > 0; off >>= 1) {
      p += __shfl_down(p, off, 64);
      n += __shfl_down(n, off, 64);
    }
    if (lane == 0) { rp[wid] = p; rn[wid] = n; }
    __syncthreads();
    if (t == 0) {
      const double P = rp[0] + rp[1] + rp[2] + rp[3];
      const double Nn = rn[0] + rn[1] + rn[2] + rn[3];
      res += P / Nn;
    }
    __syncthreads();   // rp/rn reused next b
  }
  if (t == 0) out[0] = (float)res;
}

extern "C" void kernel_launch(void* const* d_in, const int* in_sizes, int n_in,
                              void* d_out, int out_size, void* d_ws, size_t ws_size,
                              hipStream_t stream) {
  const float* style_E = (const float*)d_in[0];
  const float* style_S = (const float*)d_in[1];
  const float* trans_E = (const float*)d_in[2];
  const float* trans_S = (const float*)d_in[3];
  const int*   neg_idx = (const int*)d_in[4];

  // ws layout: Ss packed (16.8MB), Ts packed (16.8MB), pospart, negpart (16KB each)
  u32*   Ss      = (u32*)d_ws;
  u32*   Ts      = Ss + (size_t)ROWS * ROWW;
  float* pospart = (float*)(Ts + (size_t)ROWS * ROWW);
  float* negpart = pospart + ROWS;

  sort_pair<<<ROWS, NTH, 0, stream>>>(style_E, style_S, trans_E, trans_S, Ss, Ts, pospart);
  diff_rows<<<ROWS, NTH, 0, stream>>>(Ss, Ts, neg_idx, negpart);
  finalize<<<1, NTH, 0, stream>>>(pospart, negpart, (float*)d_out);
}

// Round 15
// 104.208 us; speedup vs baseline: 1.0093x; 1.0093x over previous
//
#include <hip/hip_runtime.h>

// EFDM loss — reduced form:
//   pos_sum[b]  = sum over (a,p,c,j) of (sortT[a,p,b,c][j] - sortS[a,p,b,c][j])^2
//   neg_sum[b]  = sum over (a,p,k,c,j) of (sortT[a,p,b,c][j] - sortS[a,p,nb(b,k),c][j])^2
//   out = sum_b pos_sum[b]/neg_sum[b]          (the 1/(C*N) mean factors cancel)
//
// FINAL (R13 configuration, measured 103.9 us — R14's pos-fusion + XCD-chunked
// diff regressed to 105.2, so reverted):
// Kernel 1 (sort_pair): 4096 blocks, block r sorts BOTH S-row r and T-row r in
// one instruction stream: word p = [S elem (lo fp16), T elem (hi fp16)].
// Every network op is per-half independent (pk_min/max, whole-word lane moves,
// sign-XOR masks), so two rows ride one sort. Tail passes are pure 2-op
// word-pair cswaps. Unpack at store via v_perm_b32; all rows share the same
// rank->slot map so diff is unchanged.
//  - polarized DPP/swizzle passes (pk_min with fused neg on exchanged value)
//  - TM=4 via ds_swizzle 0x101F; TM=16/32 via permlane swap butterfly
//  - LDS (TM=64/128): stride-20-word slots, proven conflict-free
// Kernel 2 (diff_rows): streaming diff, per-row partials, no atomics.
// Kernel 3 (finalize): one-block double reduction.

typedef unsigned int u32;
typedef __fp16 f16x2 __attribute__((ext_vector_type(2)));

constexpr int N     = 4096;
constexpr int NTH   = 256;
constexpr int CDIM  = 128;
constexpr int BDIM  = 4;
constexpr int KNEG  = 2;
constexpr int ROWS  = 4096;
constexpr int HALF  = 2048;
constexpr int ROWW  = N / 2;   // 2048 packed words per row
constexpr int LSTRW = 20;      // words per thread slot in LDS (80B; 16 used)
constexpr int LDSW  = NTH * LSTRW;   // 20480 B -> 8 blocks/CU

__device__ inline int lslot(int t) { return t * LSTRW; }

// ---------- packed fp16 primitives ----------
__device__ inline u32 pk_min(u32 a, u32 b) {
  u32 d; asm("v_pk_min_f16 %0, %1, %2" : "=v"(d) : "v"(a), "v"(b)); return d;
}
__device__ inline u32 pk_max(u32 a, u32 b) {
  u32 d; asm("v_pk_max_f16 %0, %1, %2" : "=v"(d) : "v"(a), "v"(b)); return d;
}
__device__ inline u32 pk_min_negb(u32 a, u32 b) {   // min(a, -b) per half
  u32 d; asm("v_pk_min_f16 %0, %1, %2 neg_lo:[0,1] neg_hi:[0,1]" : "=v"(d) : "v"(a), "v"(b)); return d;
}
__device__ inline u32 pk_sub(u32 a, u32 b) {   // a - b per half
  u32 d; asm("v_pk_add_f16 %0, %1, %2 neg_lo:[0,1] neg_hi:[0,1]" : "=v"(d) : "v"(a), "v"(b)); return d;
}
__device__ inline float dot2acc(u32 d, float acc) {  // acc += d.lo^2 + d.hi^2
  asm("v_dot2_f32_f16 %0, %1, %2, %0" : "+v"(acc) : "v"(d), "v"(d)); return acc;
}
__device__ inline void pk_cswap(u32& a, u32& b) {
  const u32 mn = pk_min(a, b), mx = pk_max(a, b);
  a = mn; b = mx;
}

// ---------- cross-lane moves ----------
// DPP ctrls: 0xB1=quad xor1, 0x4E=quad xor2, 0x128=row_ror:8 (xor8)
template<int CTRL>
__device__ inline u32 dpp_u(u32 x) {
  return (u32)__builtin_amdgcn_update_dpp((int)x, (int)x, CTRL, 0xF, 0xF, false);
}
template<int TM>
__device__ inline u32 dppx(u32 x) {   // value from lane t^TM
  if constexpr (TM == 1)      return dpp_u<0xB1>(x);
  else if constexpr (TM == 2) return dpp_u<0x4E>(x);
  else if constexpr (TM == 4)   // xor4 via ds_swizzle (DS pipe)
    return (u32)__builtin_amdgcn_ds_swizzle((int)x, 0x101F);
  else                        return dpp_u<0x128>(x);
}
__device__ inline void swap32u(u32& a, u32& b) {
  asm("v_permlane32_swap_b32 %0, %1" : "+v"(a), "+v"(b));
}
__device__ inline void swap16u(u32& a, u32& b) {
  asm("v_permlane16_swap_b32 %0, %1" : "+v"(a), "+v"(b));
}

__device__ inline void flip16(u32 h[16], u32 f) {
  #pragma unroll
  for (int p = 0; p < 16; ++p) h[p] ^= f;
}

// ---------- polarized exchange block (on 16 words) ----------
// Stored H(t) = sigma_TM(t) * x(t), sigma=+1 iff (t&TM)==0. Partner has the
// opposite sigma: H' = pk_min(H, -xchg(H)) with the negate fused.
struct PolM { u32 s1, s2, s4, s8; };

template<int TM>
__device__ inline void polar_pass16(u32 h[16]) {
  #pragma unroll
  for (int g = 0; g < 16; g += 8) {
    u32 o[8];
    #pragma unroll
    for (int p = 0; p < 8; ++p) o[p] = dppx<TM>(h[g + p]);
    #pragma unroll
    for (int p = 0; p < 8; ++p) h[g + p] = pk_min_negb(h[g + p], o[p]);
  }
}

template<int TMS, bool SKIP_ENTRY>
__device__ inline void polar_block16(u32 h[16], const PolM& pm) {
  if constexpr (!SKIP_ENTRY) {
    const u32 e = (TMS == 8) ? pm.s8 : (TMS == 4) ? pm.s4 : (TMS == 2) ? pm.s2 : pm.s1;
    flip16(h, e);
  }
  if constexpr (TMS >= 8) { polar_pass16<8>(h); flip16(h, pm.s8 ^ pm.s4); }
  if constexpr (TMS >= 4) { polar_pass16<4>(h); flip16(h, pm.s4 ^ pm.s2); }
  if constexpr (TMS >= 2) { polar_pass16<2>(h); flip16(h, pm.s2 ^ pm.s1); }
  polar_pass16<1>(h);
  flip16(h, pm.s1);   // back to plain
}

// lane-xor 16/32 butterfly on word PAIRs: positional min/max, no polarity
template<bool IS32>
__device__ inline void pass_perm16(u32 h[16]) {
  #pragma unroll
  for (int q = 0; q < 8; ++q) {
    u32 a = h[2*q], b = h[2*q + 1];
    if constexpr (IS32) swap32u(a, b); else swap16u(a, b);
    u32 mn = pk_min(a, b);
    u32 mx = pk_max(a, b);
    if constexpr (IS32) swap32u(mn, mx); else swap16u(mn, mx);
    h[2*q] = mn; h[2*q + 1] = mx;
  }
}

// thread-xor 64/128 via LDS; keep decision wave-uniform
template<int TM>
__device__ inline void pass_lds16(u32 h[16], u32* buf, int t) {
  __syncthreads();   // protect prior reads of buf
  uint4* wp = (uint4*)(buf + lslot(t));
  wp[0] = make_uint4(h[0],  h[1],  h[2],  h[3]);
  wp[1] = make_uint4(h[4],  h[5],  h[6],  h[7]);
  wp[2] = make_uint4(h[8],  h[9],  h[10], h[11]);
  wp[3] = make_uint4(h[12], h[13], h[14], h[15]);
  __syncthreads();
  const uint4* rp = (const uint4*)(buf + lslot(t ^ TM));
  const uint4 x0 = rp[0], x1 = rp[1], x2 = rp[2], x3 = rp[3];
  if (t & TM) {
    h[0]  = pk_max(h[0],  x0.x); h[1]  = pk_max(h[1],  x0.y);
    h[2]  = pk_max(h[2],  x0.z); h[3]  = pk_max(h[3],  x0.w);
    h[4]  = pk_max(h[4],  x1.x); h[5]  = pk_max(h[5],  x1.y);
    h[6]  = pk_max(h[6],  x1.z); h[7]  = pk_max(h[7],  x1.w);
    h[8]  = pk_max(h[8],  x2.x); h[9]  = pk_max(h[9],  x2.y);
    h[10] = pk_max(h[10], x2.z); h[11] = pk_max(h[11], x2.w);
    h[12] = pk_max(h[12], x3.x); h[13] = pk_max(h[13], x3.y);
    h[14] = pk_max(h[14], x3.z); h[15] = pk_max(h[15], x3.w);
  } else {
    h[0]  = pk_min(h[0],  x0.x); h[1]  = pk_min(h[1],  x0.y);
    h[2]  = pk_min(h[2],  x0.z); h[3]  = pk_min(h[3],  x0.w);
    h[4]  = pk_min(h[4],  x1.x); h[5]  = pk_min(h[5],  x1.y);
    h[6]  = pk_min(h[6],  x1.z); h[7]  = pk_min(h[7],  x1.w);
    h[8]  = pk_min(h[8],  x2.x); h[9]  = pk_min(h[9],  x2.y);
    h[10] = pk_min(h[10], x2.z); h[11] = pk_min(h[11], x2.w);
    h[12] = pk_min(h[12], x3.x); h[13] = pk_min(h[13], x3.y);
    h[14] = pk_min(h[14], x3.z); h[15] = pk_min(h[15], x3.w);
  }
}

// pre-stage passes (k<=8): direction static from word index p
template<int K, int J>
__device__ inline void local_pass16(u32 h[16]) {
  #pragma unroll
  for (int p = 0; p < 16; ++p)
    if ((p & J) == 0) {
      if ((p & K) == 0) pk_cswap(h[p], h[p ^ J]);
      else              pk_cswap(h[p ^ J], h[p]);
    }
}

// in-register ascending tail: j = 8, 4, 2, 1 — all plain word-pair cswaps
__device__ inline void tail16(u32 h[16]) {
  #pragma unroll
  for (int p = 0; p < 16; ++p) if ((p & 8) == 0) pk_cswap(h[p], h[p ^ 8]);
  #pragma unroll
  for (int p = 0; p < 16; ++p) if ((p & 4) == 0) pk_cswap(h[p], h[p ^ 4]);
  #pragma unroll
  for (int p = 0; p < 16; ++p) if ((p & 2) == 0) pk_cswap(h[p], h[p ^ 2]);
  #pragma unroll
  for (int p = 0; p < 16; ++p) if ((p & 1) == 0) pk_cswap(h[p], h[p ^ 1]);
}

// one bitonic stage of width K (>=16), in sign-flipped space
template<int K>
__device__ inline void stage16(u32 h[16], u32* buf, int t, u32& cur, const PolM& pm) {
  constexpr bool FOLD = (K >= 32 && K <= 256);   // fold polar entry into flip
  const u32 f = (K >= 4096) ? 0u : ((t & (K >> 4)) ? 0x80008000u : 0u);
  u32 m = f ^ cur;
  if constexpr (FOLD)
    m ^= (K == 256) ? pm.s8 : (K == 128) ? pm.s4 : (K == 64) ? pm.s2 : pm.s1;
  flip16(h, m);
  cur = f;
  if constexpr (K >= 4096) pass_lds16<128>(h, buf, t);
  if constexpr (K >= 2048) pass_lds16<64>(h, buf, t);
  if constexpr (K >= 1024) pass_perm16<true>(h);
  if constexpr (K >= 512)  pass_perm16<false>(h);
  if constexpr (K >= 256)      polar_block16<8, FOLD>(h, pm);
  else if constexpr (K >= 128) polar_block16<4, FOLD>(h, pm);
  else if constexpr (K >= 64)  polar_block16<2, FOLD>(h, pm);
  else if constexpr (K >= 32)  polar_block16<1, FOLD>(h, pm);
  tail16(h);
}

// kernel 1: 4096 blocks; block r sorts S-row r (lo halves) + T-row r (hi halves)
__global__ __launch_bounds__(NTH)
void sort_pair(const float* __restrict__ sE, const float* __restrict__ sS,
               const float* __restrict__ tE, const float* __restrict__ tS,
               u32* __restrict__ Ss, u32* __restrict__ Ts) {
  __shared__ u32 buf[LDSW];
  const int t = threadIdx.x, r = blockIdx.x;
  const float* srcS = (r < HALF) ? sE + (size_t)r * N : sS + (size_t)(r - HALF) * N;
  const float* srcT = (r < HALF) ? tE + (size_t)r * N : tS + (size_t)(r - HALF) * N;

  // load + pack: word p = [S elem t*16+p (lo), T elem t*16+p (hi)]
  u32 h[16];
  {
    const float4* a4 = (const float4*)srcS;
    const float4* b4 = (const float4*)srcT;
    #pragma unroll
    for (int q = 0; q < 4; ++q) {
      const float4 xa = a4[t*4 + q];
      const float4 xb = b4[t*4 + q];
      const f16x2 p0 = __builtin_amdgcn_cvt_pkrtz(xa.x, xb.x);
      const f16x2 p1 = __builtin_amdgcn_cvt_pkrtz(xa.y, xb.y);
      const f16x2 p2 = __builtin_amdgcn_cvt_pkrtz(xa.z, xb.z);
      const f16x2 p3 = __builtin_amdgcn_cvt_pkrtz(xa.w, xb.w);
      h[q*4+0] = __builtin_bit_cast(u32, p0);
      h[q*4+1] = __builtin_bit_cast(u32, p1);
      h[q*4+2] = __builtin_bit_cast(u32, p2);
      h[q*4+3] = __builtin_bit_cast(u32, p3);
    }
  }

  // pre-stages k=2,4,8 (directions static by word index; desc = swapped args)
  local_pass16<2, 1>(h);
  local_pass16<4, 2>(h); local_pass16<4, 1>(h);
  local_pass16<8, 4>(h); local_pass16<8, 2>(h); local_pass16<8, 1>(h);

  const u32 S = 0x80008000u;
  PolM pm;
  pm.s1 = (t & 1) ? S : 0u;  pm.s2 = (t & 2) ? S : 0u;
  pm.s4 = (t & 4) ? S : 0u;  pm.s8 = (t & 8) ? S : 0u;

  u32 cur = 0;
  stage16<16>(h, buf, t, cur, pm);
  stage16<32>(h, buf, t, cur, pm);
  stage16<64>(h, buf, t, cur, pm);
  stage16<128>(h, buf, t, cur, pm);
  stage16<256>(h, buf, t, cur, pm);
  stage16<512>(h, buf, t, cur, pm);
  stage16<1024>(h, buf, t, cur, pm);
  stage16<2048>(h, buf, t, cur, pm);
  stage16<4096>(h, buf, t, cur, pm);
  // cur == 0 at the end (stage 4096 has f == 0 for all t)

  // unpack: A-word q = [lo(h[2q]), lo(h[2q+1])], B-word q = [hi(h[2q]), hi(h[2q+1])]
  u32 A[8], B[8];
  #pragma unroll
  for (int q = 0; q < 8; ++q) {
    A[q] = __builtin_amdgcn_perm(h[2*q+1], h[2*q], 0x05040100u);
    B[q] = __builtin_amdgcn_perm(h[2*q+1], h[2*q], 0x07060302u);
  }
  uint4* dA = (uint4*)(Ss + (size_t)r * ROWW);
  uint4* dB = (uint4*)(Ts + (size_t)r * ROWW);
  dA[t]       = make_uint4(A[0], A[1], A[2], A[3]);
  dA[NTH + t] = make_uint4(A[4], A[5], A[6], A[7]);
  dB[t]       = make_uint4(B[0], B[1], B[2], B[3]);
  dB[NTH + t] = make_uint4(B[4], B[5], B[6], B[7]);
}

// kernel 2: streaming diff; per-row partials, no atomics
__global__ __launch_bounds__(NTH)
void diff_rows(const u32* __restrict__ Ss, const u32* __restrict__ Ts,
               const int* __restrict__ neg_idx, float2* __restrict__ partial) {
  __shared__ float red[2][4];
  const int t = threadIdx.x, r = blockIdx.x;

  const uint4* tp = (const uint4*)(Ts + (size_t)r * ROWW);
  const uint4 h0 = tp[t], h1 = tp[NTH + t];

  // r = ((ap)*B + b)*C + c
  const int c  = r & (CDIM - 1);
  const int b  = (r / CDIM) & (BDIM - 1);
  const int ap = r / (CDIM * BDIM);

  float posp = 0.f, negp = 0.f;
  {
    const uint4* vp = (const uint4*)(Ss + (size_t)r * ROWW);
    const uint4 w0 = vp[t], w1 = vp[NTH + t];
    posp = dot2acc(pk_sub(h0.x, w0.x), posp);
    posp = dot2acc(pk_sub(h0.y, w0.y), posp);
    posp = dot2acc(pk_sub(h0.z, w0.z), posp);
    posp = dot2acc(pk_sub(h0.w, w0.w), posp);
    posp = dot2acc(pk_sub(h1.x, w1.x), posp);
    posp = dot2acc(pk_sub(h1.y, w1.y), posp);
    posp = dot2acc(pk_sub(h1.z, w1.z), posp);
    posp = dot2acc(pk_sub(h1.w, w1.w), posp);
  }
  #pragma unroll
  for (int k = 0; k < KNEG; ++k) {
    const int nb = neg_idx[b * KNEG + k];
    const uint4* vp = (const uint4*)(Ss + ((size_t)(ap * BDIM + nb) * CDIM + c) * ROWW);
    const uint4 w0 = vp[t], w1 = vp[NTH + t];
    negp = dot2acc(pk_sub(h0.x, w0.x), negp);
    negp = dot2acc(pk_sub(h0.y, w0.y), negp);
    negp = dot2acc(pk_sub(h0.z, w0.z), negp);
    negp = dot2acc(pk_sub(h0.w, w0.w), negp);
    negp = dot2acc(pk_sub(h1.x, w1.x), negp);
    negp = dot2acc(pk_sub(h1.y, w1.y), negp);
    negp = dot2acc(pk_sub(h1.z, w1.z), negp);
    negp = dot2acc(pk_sub(h1.w, w1.w), negp);
  }

  #pragma unroll
  for (int off = 32; off > 0; off >>= 1) {
    posp += __shfl_down(posp, off, 64);
    negp += __shfl_down(negp, off, 64);
  }
  const int wid = t >> 6, lane = t & 63;
  if (lane == 0) { red[0][wid] = posp; red[1][wid] = negp; }
  __syncthreads();
  if (t == 0) {
    const float pt = red[0][0] + red[0][1] + red[0][2] + red[0][3];
    const float nt = red[1][0] + red[1][1] + red[1][2] + red[1][3];
    partial[r] = make_float2(pt, nt);
  }
}

// kernel 3: single-block reduction of 4096 partials, keyed by b
__global__ __launch_bounds__(NTH)
void finalize(const float2* __restrict__ partial, float* __restrict__ out) {
  __shared__ double rp[4], rn[4];
  const int t = threadIdx.x;
  const int wid = t >> 6, lane = t & 63;
  double res = 0.0;
  #pragma unroll
  for (int b = 0; b < BDIM; ++b) {
    double p = 0.0, n = 0.0;
    for (int idx = t; idx < 1024; idx += NTH) {     // 8 ap-chunks x 128 c
      const int a = idx >> 7, c = idx & 127;
      const float2 v = partial[a * 512 + b * 128 + c];
      p += (double)v.x; n += (double)v.y;
    }
    #pragma unroll
    for (int off = 32; off > 0; off >>= 1) {
      p += __shfl_down(p, off, 64);
      n += __shfl_down(n, off, 64);
    }
    if (lane == 0) { rp[wid] = p; rn[wid] = n; }
    __syncthreads();
    if (t == 0) {
      const double P = rp[0] + rp[1] + rp[2] + rp[3];
      const double Nn = rn[0] + rn[1] + rn[2] + rn[3];
      res += P / Nn;
    }
    __syncthreads();   // rp/rn reused next b
  }
  if (t == 0) out[0] = (float)res;
}

extern "C" void kernel_launch(void* const* d_in, const int* in_sizes, int n_in,
                              void* d_out, int out_size, void* d_ws, size_t ws_size,
                              hipStream_t stream) {
  const float* style_E = (const float*)d_in[0];
  const float* style_S = (const float*)d_in[1];
  const float* trans_E = (const float*)d_in[2];
  const float* trans_S = (const float*)d_in[3];
  const int*   neg_idx = (const int*)d_in[4];

  // ws layout: Ss packed (16.8MB), Ts packed (16.8MB), partial (32KB)
  u32*    Ss      = (u32*)d_ws;
  u32*    Ts      = Ss + (size_t)ROWS * ROWW;
  float2* partial = (float2*)(Ts + (size_t)ROWS * ROWW);

  sort_pair<<<ROWS, NTH, 0, stream>>>(style_E, style_S, trans_E, trans_S, Ss, Ts);
  diff_rows<<<ROWS, NTH, 0, stream>>>(Ss, Ts, neg_idx, partial);
  finalize<<<1, NTH, 0, stream>>>(partial, (float*)d_out);
}